// Round 6
// baseline (435.567 us; speedup 1.0000x reference)
//
#include <hip/hip_runtime.h>
#include <hip/hip_fp16.h>
#include <cstddef>
#include <cstdint>

#define N_PTS 16384
#define K_PTS 1024
#define D_DIM 512
#define EPS_F 0.1f
#define ITERS 20
#define MU_F (1.0f/16384.0f)
#define NU_F (1.0f/1024.0f)
#define NCOPY 4
#define SINK_BLOCKS 256
#define SINK_THREADS 1024
#define FLAG_STRIDE 16   // 64B padding per flag
#define ACC_TOTAL ((ITERS + 1) * NCOPY * K_PTS)

typedef float f32x4 __attribute__((ext_vector_type(4)));
typedef short s16x8 __attribute__((ext_vector_type(8)));

__device__ __forceinline__ float wave_reduce_sum(float s) {
#pragma unroll
  for (int off = 32; off > 0; off >>= 1) s += __shfl_xor(s, off, 64);
  return s;
}
__device__ __forceinline__ float wave_reduce_max(float s) {
#pragma unroll
  for (int off = 32; off > 0; off >>= 1) s = fmaxf(s, __shfl_xor(s, off, 64));
  return s;
}

// ---------------------------------------------------------------- init
__global__ __launch_bounds__(256) void init_kernel(float* __restrict__ accum,
                                                   unsigned int* __restrict__ flags,
                                                   unsigned int* __restrict__ maxbits,
                                                   float* __restrict__ loss) {
  int i = blockIdx.x * 256 + threadIdx.x;
  if (i < ACC_TOTAL) accum[i] = 0.0f;
  if (i < SINK_BLOCKS * FLAG_STRIDE) flags[i] = 0u;
  if (i == 0) { *maxbits = 0u; *loss = 0.0f; }
}

// ---------------------------------------------------------------- split-bf16 MFMA GEMM
// C(fp16 -> d_out scratch) = |x|^2 + |p|^2 - 2*x@p^T; norms fused; global max tracked.
// LDS: XOR-swizzled granules (8 halfs), row stride 32 halfs, no padding.
__global__ __launch_bounds__(256) void gemm_kernel(const float* __restrict__ X,
                                                   const float* __restrict__ P,
                                                   __half* __restrict__ Ch,
                                                   unsigned int* __restrict__ maxbits) {
  __shared__ __align__(16) unsigned short Ah[128 * 32];
  __shared__ __align__(16) unsigned short Al[128 * 32];
  __shared__ __align__(16) unsigned short Bh[128 * 32];
  __shared__ __align__(16) unsigned short Bl[128 * 32];
  __shared__ float dxs[128];
  __shared__ float pns[128];

  const int tid = threadIdx.x;
  const int lane = tid & 63, wv = tid >> 6;
  const int wm = wv >> 1, wn = wv & 1;
  const int m0 = blockIdx.y * 128, k0 = blockIdx.x * 128;
  const int lrow = tid >> 1, lhalf = tid & 1;

  const float* xrow = X + (size_t)(m0 + lrow) * D_DIM + lhalf * 16;
  const float* prow = P + (size_t)(k0 + lrow) * D_DIM + lhalf * 16;
  const int sw = (lrow >> 1) & 3;                 // per-row granule swizzle
  const int woff0 = lrow * 32 + ((2 * lhalf + 0) ^ sw) * 8;
  const int woff1 = lrow * 32 + ((2 * lhalf + 1) ^ sw) * 8;

  f32x4 acc[4][4] = {};
  float sx = 0.f, sp = 0.f;

  for (int d0 = 0; d0 < D_DIM; d0 += 32) {
    float av[16], bv[16];
    {
      const float4* xp = (const float4*)(xrow + d0);
      const float4* pp = (const float4*)(prow + d0);
#pragma unroll
      for (int q = 0; q < 4; q++) {
        float4 a = xp[q], b = pp[q];
        av[q*4+0]=a.x; av[q*4+1]=a.y; av[q*4+2]=a.z; av[q*4+3]=a.w;
        bv[q*4+0]=b.x; bv[q*4+1]=b.y; bv[q*4+2]=b.z; bv[q*4+3]=b.w;
      }
    }
#pragma unroll
    for (int q = 0; q < 16; q++) { sx += av[q] * av[q]; sp += bv[q] * bv[q]; }
    // truncate-split: hi = trunc16(f), lo = bf16(f - hi); pack pairs via v_perm
    unsigned int ahu[8], alu[8], bhu[8], blu[8];
#pragma unroll
    for (int j = 0; j < 8; j++) {
      unsigned int a0 = __float_as_uint(av[2*j]), a1 = __float_as_uint(av[2*j+1]);
      ahu[j] = __builtin_amdgcn_perm(a1, a0, 0x07060302u);
      unsigned int l0 = __float_as_uint(av[2*j]   - __uint_as_float(a0 & 0xffff0000u));
      unsigned int l1 = __float_as_uint(av[2*j+1] - __uint_as_float(a1 & 0xffff0000u));
      alu[j] = __builtin_amdgcn_perm(l1, l0, 0x07060302u);
      unsigned int b0 = __float_as_uint(bv[2*j]), b1 = __float_as_uint(bv[2*j+1]);
      bhu[j] = __builtin_amdgcn_perm(b1, b0, 0x07060302u);
      unsigned int m0u = __float_as_uint(bv[2*j]   - __uint_as_float(b0 & 0xffff0000u));
      unsigned int m1u = __float_as_uint(bv[2*j+1] - __uint_as_float(b1 & 0xffff0000u));
      blu[j] = __builtin_amdgcn_perm(m1u, m0u, 0x07060302u);
    }
    __syncthreads();  // protect previous iteration's fragment reads
    *(uint4*)&Ah[woff0] = make_uint4(ahu[0], ahu[1], ahu[2], ahu[3]);
    *(uint4*)&Ah[woff1] = make_uint4(ahu[4], ahu[5], ahu[6], ahu[7]);
    *(uint4*)&Al[woff0] = make_uint4(alu[0], alu[1], alu[2], alu[3]);
    *(uint4*)&Al[woff1] = make_uint4(alu[4], alu[5], alu[6], alu[7]);
    *(uint4*)&Bh[woff0] = make_uint4(bhu[0], bhu[1], bhu[2], bhu[3]);
    *(uint4*)&Bh[woff1] = make_uint4(bhu[4], bhu[5], bhu[6], bhu[7]);
    *(uint4*)&Bl[woff0] = make_uint4(blu[0], blu[1], blu[2], blu[3]);
    *(uint4*)&Bl[woff1] = make_uint4(blu[4], blu[5], blu[6], blu[7]);
    __syncthreads();

    s16x8 ah[4], al[4], bh[4], bl[4];
#pragma unroll
    for (int i = 0; i < 4; i++) {
      int rA = wm * 64 + i * 16 + (lane & 15);
      int gA = (lane >> 4) ^ ((rA >> 1) & 3);
      ah[i] = *(const s16x8*)&Ah[rA * 32 + gA * 8];
      al[i] = *(const s16x8*)&Al[rA * 32 + gA * 8];
      int rB = wn * 64 + i * 16 + (lane & 15);
      int gB = (lane >> 4) ^ ((rB >> 1) & 3);
      bh[i] = *(const s16x8*)&Bh[rB * 32 + gB * 8];
      bl[i] = *(const s16x8*)&Bl[rB * 32 + gB * 8];
    }
#pragma unroll
    for (int mi = 0; mi < 4; mi++)
#pragma unroll
      for (int ni = 0; ni < 4; ni++) {
        acc[mi][ni] = __builtin_amdgcn_mfma_f32_16x16x32_bf16(ah[mi], bh[ni], acc[mi][ni], 0, 0, 0);
        acc[mi][ni] = __builtin_amdgcn_mfma_f32_16x16x32_bf16(ah[mi], bl[ni], acc[mi][ni], 0, 0, 0);
        acc[mi][ni] = __builtin_amdgcn_mfma_f32_16x16x32_bf16(al[mi], bh[ni], acc[mi][ni], 0, 0, 0);
      }
  }

  // publish fused norms (pair-halves combined via adjacent-lane shuffle)
  float px = sx + __shfl_xor(sx, 1, 64);
  float pp2 = sp + __shfl_xor(sp, 1, 64);
  __syncthreads();
  dxs[lrow] = px;
  pns[lrow] = pp2;
  __syncthreads();

  // epilogue: C/D layout col=lane&15, row=(lane>>4)*4+reg
  float lmax = -3.4e38f;
#pragma unroll
  for (int mi = 0; mi < 4; mi++) {
    int rloc = wm * 64 + mi * 16 + (lane >> 4) * 4;
    float dxv[4];
#pragma unroll
    for (int r = 0; r < 4; r++) dxv[r] = dxs[rloc + r];
#pragma unroll
    for (int ni = 0; ni < 4; ni++) {
      int cloc = wn * 64 + ni * 16 + (lane & 15);
      float pnc = pns[cloc];
#pragma unroll
      for (int r = 0; r < 4; r++) {
        float val = dxv[r] + pnc - 2.0f * acc[mi][ni][r];
        Ch[(size_t)(m0 + rloc + r) * K_PTS + k0 + cloc] = __float2half(val);
        lmax = fmaxf(lmax, val);
      }
    }
  }
  lmax = wave_reduce_max(lmax);
  __shared__ float wmax[4];
  if (lane == 0) wmax[wv] = lmax;
  __syncthreads();
  if (tid == 0) {
    float m = fmaxf(fmaxf(wmax[0], wmax[1]), fmaxf(wmax[2], wmax[3]));
    atomicMax((int*)maxbits, __float_as_int(m));  // global max is positive
  }
}

// ---------------------------------------------------------------- persistent Sinkhorn, fully fused
// 256 blocks x 1024 threads (16 waves, 1 block/CU). Wave wv owns rows r0..r0+4;
// lane owns cols [lane*16, lane*16+16). K = exp(C*factor) in 16 f32x4 regs/lane.
// All LDS traffic is b128/b32 conflict-free. One atomicAdd/thread/iter (NCOPY=4,
// [col][copy] layout -> readback is two 8B agent loads). Flag barrier per iter.
__global__ __launch_bounds__(SINK_THREADS, 4) void sinkhorn_kernel(
    const __half* __restrict__ Ch,
    const unsigned int* __restrict__ maxbits,
    float* __restrict__ accum,          // (ITERS+1) stages x K_PTS x NCOPY
    unsigned int* __restrict__ flags,   // SINK_BLOCKS x FLAG_STRIDE
    float* __restrict__ T,
    float* __restrict__ loss) {
  __shared__ float v_lds[K_PTS];
  __shared__ float red[16][K_PTS];
  const int tid = threadIdx.x;
  const int lane = tid & 63, wv = tid >> 6;
  const int b = blockIdx.x;
  const int r0 = b * 64 + wv * 4;

  float factor;
  {
    float cmax = __int_as_float((int)*maxbits);
    factor = -1.0f / ((cmax + 1e-8f) * EPS_F);
  }
  // preamble: coalesced load of 4 fp16 rows (32B/lane/row), K into 16 f32x4 regs
  f32x4 k4[16];
#pragma unroll
  for (int i = 0; i < 4; i++) {
    const uint4* rp = (const uint4*)(Ch + (size_t)(r0 + i) * K_PTS + lane * 16);
    uint4 w0 = rp[0], w1 = rp[1];
    const __half2* h0 = (const __half2*)&w0;
    const __half2* h1 = (const __half2*)&w1;
#pragma unroll
    for (int q = 0; q < 2; q++) {
      f32x4 kk;
      float2 c0 = __half22float2(h0[2*q+0]);
      float2 c1 = __half22float2(h0[2*q+1]);
      kk[0] = __expf(c0.x * factor); kk[1] = __expf(c0.y * factor);
      kk[2] = __expf(c1.x * factor); kk[3] = __expf(c1.y * factor);
      k4[i * 4 + q] = kk;
      f32x4 km;
      float2 d0 = __half22float2(h1[2*q+0]);
      float2 d1 = __half22float2(h1[2*q+1]);
      km[0] = __expf(d0.x * factor); km[1] = __expf(d0.y * factor);
      km[2] = __expf(d1.x * factor); km[3] = __expf(d1.y * factor);
      k4[i * 4 + 2 + q] = km;
    }
  }
  v_lds[tid] = 1.0f;
  __syncthreads();

  float su[4];
  for (int t = 0; t < ITERS; t++) {
    f32x4 vr4[4];
#pragma unroll
    for (int q = 0; q < 4; q++)
      vr4[q] = *(const f32x4*)&v_lds[lane * 16 + q * 4];   // ds_read_b128, conflict-free

    float s[4];
#pragma unroll
    for (int i = 0; i < 4; i++) {
      f32x4 d = k4[i * 4 + 0] * vr4[0] + k4[i * 4 + 1] * vr4[1]
              + k4[i * 4 + 2] * vr4[2] + k4[i * 4 + 3] * vr4[3];
      s[i] = d[0] + d[1] + d[2] + d[3];
    }
    // routed reduce: 7 shuffles for 4 rows; group g=lane>>4 ends holding row g.
    {
      const bool h32 = (lane & 32) != 0;
      float a[2];
#pragma unroll
      for (int i = 0; i < 2; i++) {
        float x = h32 ? s[i] : s[i + 2];
        float y = h32 ? s[i + 2] : s[i];
        a[i] = y + __shfl_xor(x, 32, 64);
      }
      const bool h16 = (lane & 16) != 0;
      float x = h16 ? a[0] : a[1];
      float y = h16 ? a[1] : a[0];
      float w = y + __shfl_xor(x, 16, 64);
      w += __shfl_xor(w, 8, 64);
      w += __shfl_xor(w, 4, 64);
      w += __shfl_xor(w, 2, 64);
      w += __shfl_xor(w, 1, 64);
      float ui_local = MU_F / (w + 1e-8f);
#pragma unroll
      for (int i = 0; i < 4; i++)
        su[i] = __uint_as_float(__builtin_amdgcn_readlane(__float_as_uint(ui_local), i * 16));
    }
    f32x4 ca4[4] = {};
#pragma unroll
    for (int i = 0; i < 4; i++)
#pragma unroll
      for (int q = 0; q < 4; q++)
        ca4[q] += su[i] * k4[i * 4 + q];

#pragma unroll
    for (int q = 0; q < 4; q++)
      *(f32x4*)&red[wv][lane * 16 + q * 4] = ca4[q];       // ds_write_b128, own slice
    __syncthreads();
    {
      float cs = 0.f;
#pragma unroll
      for (int w16 = 0; w16 < 16; w16++) cs += red[w16][tid];
      atomicAdd(accum + (size_t)(t + 1) * (K_PTS * NCOPY) + tid * NCOPY + (b & (NCOPY - 1)), cs);
    }
    __syncthreads();  // every thread's atomic drained (vmcnt) before arrival
    if (tid == 0)
      __hip_atomic_store(&flags[(size_t)b * FLAG_STRIDE], (unsigned)(t + 1),
                         __ATOMIC_RELEASE, __HIP_MEMORY_SCOPE_AGENT);
    if (tid < SINK_BLOCKS) {
      while (__hip_atomic_load(&flags[(size_t)tid * FLAG_STRIDE],
                               __ATOMIC_RELAXED, __HIP_MEMORY_SCOPE_AGENT) < (unsigned)(t + 1))
        __builtin_amdgcn_s_sleep(1);
    }
    __syncthreads();
    {
      const unsigned long long* st = (const unsigned long long*)
          (accum + (size_t)(t + 1) * (K_PTS * NCOPY) + tid * NCOPY);
      unsigned long long p0 = __hip_atomic_load(st + 0, __ATOMIC_RELAXED, __HIP_MEMORY_SCOPE_AGENT);
      unsigned long long p1 = __hip_atomic_load(st + 1, __ATOMIC_RELAXED, __HIP_MEMORY_SCOPE_AGENT);
      float2 f0 = *(float2*)&p0;
      float2 f1 = *(float2*)&p1;
      v_lds[tid] = NU_F / (f0.x + f0.y + f1.x + f1.y + 1e-8f);
    }
    __syncthreads();
  }

  // final: T = u*k*v from registers (b128 coalesced stores); loss = sum(T * (-eps*ln k)).
  // d_out clobber safe: all Ch reads happened before barrier 1.
  float lsum = 0.f;
#pragma unroll
  for (int i = 0; i < 4; i++) {
    float* Trow = T + (size_t)(r0 + i) * K_PTS + lane * 16;
#pragma unroll
    for (int q = 0; q < 4; q++) {
      f32x4 vv = *(const f32x4*)&v_lds[lane * 16 + q * 4];
      f32x4 kk = k4[i * 4 + q];
      f32x4 tv = su[i] * kk * vv;
      *(f32x4*)&Trow[q * 4] = tv;
      lsum += tv[0] * (-EPS_F * __logf(kk[0]));
      lsum += tv[1] * (-EPS_F * __logf(kk[1]));
      lsum += tv[2] * (-EPS_F * __logf(kk[2]));
      lsum += tv[3] * (-EPS_F * __logf(kk[3]));
    }
  }
  lsum = wave_reduce_sum(lsum);
  __shared__ float wsum[16];
  if (lane == 0) wsum[wv] = lsum;
  __syncthreads();
  if (tid == 0) {
    float m = 0.f;
#pragma unroll
    for (int i = 0; i < 16; i++) m += wsum[i];
    atomicAdd(loss, m);
  }
}

// ---------------------------------------------------------------- launcher
extern "C" void kernel_launch(void* const* d_in, const int* in_sizes, int n_in,
                              void* d_out, int out_size, void* d_ws, size_t ws_size,
                              hipStream_t stream) {
  const float* x = (const float*)d_in[0];
  const float* p = (const float*)d_in[1];
  float* T = (float*)d_out;
  float* loss = (float*)d_out + (size_t)N_PTS * K_PTS;
  __half* Ch = (__half*)d_out;  // fp16 C staged in d_out between gemm and sinkhorn

  float* accum = (float*)d_ws;                                   // ACC_TOTAL floats
  unsigned int* flags = (unsigned int*)(accum + ACC_TOTAL);      // 256*16
  unsigned int* maxbits = flags + SINK_BLOCKS * FLAG_STRIDE;

  init_kernel<<<(ACC_TOTAL + 255) / 256, 256, 0, stream>>>(accum, flags, maxbits, loss);
  gemm_kernel<<<dim3(K_PTS / 128, N_PTS / 128), 256, 0, stream>>>(x, p, Ch, maxbits);
  sinkhorn_kernel<<<SINK_BLOCKS, SINK_THREADS, 0, stream>>>(Ch, maxbits, accum, flags, T, loss);
}